// Round 26
// baseline (137.116 us; speedup 1.0000x reference)
//
#include <hip/hip_runtime.h>
#include <hip/hip_bf16.h>

// Shapes (fixed by the reference)
#define BB 16
#define HH 64
#define WW 64
#define CC 256
#define OH 128
#define OW 128
#define FF 256

typedef __attribute__((ext_vector_type(8))) short bf16x8;
typedef __attribute__((ext_vector_type(4))) float f32x4;

// RNE float -> bf16 bits
__device__ __forceinline__ short f2bf(float x) {
    union { float f; unsigned u; } v; v.f = x;
    unsigned r = v.u + 0x7fffu + ((v.u >> 16) & 1u);
    return (short)(r >> 16);
}

// packed f32x2 -> bf16x2 (1 VALU instr)
__device__ __forceinline__ unsigned cvtpk(float lo, float hi) {
    unsigned r;
    asm("v_cvt_pk_bf16_f32 %0, %1, %2" : "=v"(r) : "v"(lo), "v"(hi));
    return r;
}

// prep: 32 blocks build pwtF = pw in MFMA fragment-linear order:
//   entry e = ((wc*8 + kk)*4 + ni)*64 + lane (bf16x8); holds pw[c0..c0+7][f]
//   with f = wc*64+ni*16+(lane&15), c0 = kk*32+(lane>>4)*8.
__global__ void prep_kernel(const float* __restrict__ pw, short* __restrict__ pwtF) {
    const int e    = blockIdx.x * 256 + threadIdx.x;
    const int lane = e & 63;
    const int ni   = (e >> 6) & 3;
    const int kk   = (e >> 8) & 7;
    const int wc   = e >> 11;
    const int f    = wc * 64 + ni * 16 + (lane & 15);
    const int c0   = kk * 32 + (lane >> 4) * 8;
    bf16x8 v;
    #pragma unroll
    for (int j = 0; j < 8; ++j) v[j] = f2bf(pw[(size_t)(c0 + j) * FF + f]);
    reinterpret_cast<bf16x8*>(pwtF)[e] = v;
}

// One block = one (b, oh) output row, 4 quarters of 32 ow.
// Waves 0-3 = producers: wave-private global_load_lds X staging (counted vmcnt)
//   + depthwise from LDS -> t_lds[q&1]. Wave w owns ow chunk [q*32+w*8, +8),
//   lane owns 4 channels -> all staging/reads perfectly linear, and each wave
//   reads ONLY the xraw window it staged itself (per-wave vmcnt is sound).
// Waves 4-7 = consumers: MFMA pointwise (fragment-linear B) + f32x4 stores,
//   with s_setprio(1) around the MFMA cluster (T5: role-split structure =
//   the documented prerequisite for setprio to pay).
// Raw s_barrier (asm, memory clobber) between quarters; vmcnt never drained.
__global__ __launch_bounds__(512, 2)
void sepconvt_kernel(const float* __restrict__ X,
                     const float* __restrict__ dw,
                     const short* __restrict__ pwtF,
                     const float* __restrict__ bias,
                     float* __restrict__ out) {
    __shared__ __align__(16) char xraw[98304];     // 2 bufs x 4 waves x [2 rows][6 cols][256ch f32]
    __shared__ bf16x8 t_lds[2][32 * 32];           // 2 x 16 KiB

    const int tid  = threadIdx.x;
    const int wid  = tid >> 6;
    const int lane = tid & 63;
    const int blk  = blockIdx.x;          // b*OH + oh
    const int oh = blk & (OH - 1);
    const int b  = blk >> 7;

    // Row taps: even oh -> (r=1, i=oh/2), (r=3, i=oh/2-1); odd -> (r=0,(oh+1)/2),(r=2,(oh-1)/2)
    int r0, r1, i0, i1;
    if (oh & 1) { r0 = 0; i0 = (oh + 1) >> 1; r1 = 2; i1 = (oh - 1) >> 1; }
    else        { r0 = 1; i0 = oh >> 1;       r1 = 3; i1 = (oh >> 1) - 1; }
    const bool va0 = (unsigned)i0 < HH;
    const bool va1 = (unsigned)i1 < HH;

    if (wid < 4) {
        // ---------------- producer persona ----------------
        const int w  = wid;
        const int c4 = lane << 2;         // 4-channel base
        const float* Xr0 = X + (size_t)(b * HH + (va0 ? i0 : 0)) * WW * CC + c4;
        const float* Xr1 = X + (size_t)(b * HH + (va1 ? i1 : 0)) * WW * CC + c4;

        // weights wt[row][p][tap]: p=0 even ow (je=s1, jo=s3), p=1 odd (je=s0, jo=s2)
        float4 wt[2][2][2];
        {
            const float4 z = {0.f, 0.f, 0.f, 0.f};
            #pragma unroll
            for (int r = 0; r < 2; ++r) {
                const int rr = r ? r1 : r0;
                const bool va = r ? va1 : va0;
                float4 s0 = *reinterpret_cast<const float4*>(dw + (rr * 4 + 0) * CC + c4);
                float4 s1 = *reinterpret_cast<const float4*>(dw + (rr * 4 + 1) * CC + c4);
                float4 s2 = *reinterpret_cast<const float4*>(dw + (rr * 4 + 2) * CC + c4);
                float4 s3 = *reinterpret_cast<const float4*>(dw + (rr * 4 + 3) * CC + c4);
                wt[r][0][0] = va ? s1 : z;
                wt[r][0][1] = va ? s3 : z;
                wt[r][1][0] = va ? s0 : z;
                wt[r][1][1] = va ? s2 : z;
            }
        }

        // stage quarter q's wave-private window into buffer qb (12 x 1KB DMA)
        auto STAGE = [&](int q, int qb) {
            const int W0  = q * 32 + w * 8;
            const int jlo = (W0 >> 1) - 1;
            const int base = qb * 49152 + w * 12288;
            #pragma unroll
            for (int ci = 0; ci < 6; ++ci) {
                int j = jlo + ci;
                j = j < 0 ? 0 : (j > WW - 1 ? WW - 1 : j);
                __builtin_amdgcn_global_load_lds(
                    (const __attribute__((address_space(1))) unsigned*)(Xr0 + (size_t)j * CC),
                    (__attribute__((address_space(3))) unsigned*)(xraw + base + ci * 1024),
                    16, 0, 0);
                __builtin_amdgcn_global_load_lds(
                    (const __attribute__((address_space(1))) unsigned*)(Xr1 + (size_t)j * CC),
                    (__attribute__((address_space(3))) unsigned*)(xraw + base + 6144 + ci * 1024),
                    16, 0, 0);
            }
        };

        auto LC = [&](const char* xw, int ci, float4& x0, float4& x1) {
            x0 = *reinterpret_cast<const float4*>(xw + ci * 1024 + lane * 16);
            x1 = *reinterpret_cast<const float4*>(xw + 6144 + ci * 1024 + lane * 16);
        };

        auto EMIT = [&](int qb, int owl, int p,
                        const float4& xe0, const float4& xe1,
                        const float4& xo0, const float4& xo1) {
            const float4 we0 = wt[0][p][0], wo0 = wt[0][p][1];
            const float4 we1 = wt[1][p][0], wo1 = wt[1][p][1];
            float a0 = we0.x * xe0.x + wo0.x * xo0.x + we1.x * xe1.x + wo1.x * xo1.x;
            float a1 = we0.y * xe0.y + wo0.y * xo0.y + we1.y * xe1.y + wo1.y * xo1.y;
            float a2 = we0.z * xe0.z + wo0.z * xo0.z + we1.z * xe1.z + wo1.z * xo1.z;
            float a3 = we0.w * xe0.w + wo0.w * xo0.w + we1.w * xe1.w + wo1.w * xo1.w;
            unsigned* dst = reinterpret_cast<unsigned*>(
                reinterpret_cast<char*>(&t_lds[qb][0]) + owl * 512 +
                (((lane >> 1) ^ (owl & 7)) << 4) + ((lane & 1) << 3));
            dst[0] = cvtpk(a0, a1);
            dst[1] = cvtpk(a2, a3);
        };

        auto PRODUCE = [&](int q, int qb) {
            const char* xw = xraw + qb * 49152 + w * 12288;
            const int W0 = q * 32 + w * 8;
            const int o0 = w * 8;
            float4 xo0, xo1, xe0, xe1;
            LC(xw, 0, xo0, xo1);
            LC(xw, 1, xe0, xe1);
            if (W0 == 0) { xo0 = (float4){0,0,0,0}; xo1 = (float4){0,0,0,0}; }
            EMIT(qb, o0 + 0, 0, xe0, xe1, xo0, xo1);
            xo0 = xe0; xo1 = xe1; LC(xw, 2, xe0, xe1);
            EMIT(qb, o0 + 1, 1, xe0, xe1, xo0, xo1);
            EMIT(qb, o0 + 2, 0, xe0, xe1, xo0, xo1);
            xo0 = xe0; xo1 = xe1; LC(xw, 3, xe0, xe1);
            EMIT(qb, o0 + 3, 1, xe0, xe1, xo0, xo1);
            EMIT(qb, o0 + 4, 0, xe0, xe1, xo0, xo1);
            xo0 = xe0; xo1 = xe1; LC(xw, 4, xe0, xe1);
            EMIT(qb, o0 + 5, 1, xe0, xe1, xo0, xo1);
            EMIT(qb, o0 + 6, 0, xe0, xe1, xo0, xo1);
            xo0 = xe0; xo1 = xe1; LC(xw, 5, xe0, xe1);
            if (W0 == 120) { xe0 = (float4){0,0,0,0}; xe1 = (float4){0,0,0,0}; }
            EMIT(qb, o0 + 7, 1, xe0, xe1, xo0, xo1);
        };

        STAGE(0, 0);
        #pragma unroll
        for (int q = 0; q < 4; ++q) {
            if (q < 3) {
                STAGE(q + 1, (q + 1) & 1);
                asm volatile("s_waitcnt vmcnt(12)" ::: "memory");  // own S(q) landed; S(q+1) in flight
            } else {
                asm volatile("s_waitcnt vmcnt(0)" ::: "memory");
            }
            __builtin_amdgcn_sched_barrier(0);
            PRODUCE(q, q & 1);
            asm volatile("s_waitcnt lgkmcnt(0)" ::: "memory");     // own t_lds writes drained
            __builtin_amdgcn_sched_barrier(0);
            asm volatile("s_barrier" ::: "memory");                // tile q ready
        }
    } else {
        // ---------------- consumer persona ----------------
        const int wc  = wid - 4;          // 0..3 -> f block
        const int lr  = lane & 15;
        const int lk8 = lane >> 4;
        const bf16x8* pvF = reinterpret_cast<const bf16x8*>(pwtF) + (size_t)wc * 2048 + lane;

        f32x4 bv[4];
        #pragma unroll
        for (int ni = 0; ni < 4; ++ni)
            bv[ni] = *reinterpret_cast<const f32x4*>(&bias[wc * 64 + ni * 16 + lk8 * 4]);

        #pragma unroll
        for (int q = 0; q < 4; ++q) {
            asm volatile("s_barrier" ::: "memory");    // wait tile q
            __builtin_amdgcn_sched_barrier(0);
            const int qb = q & 1;

            f32x4 acc[2][4];
            #pragma unroll
            for (int mi = 0; mi < 2; ++mi)
                #pragma unroll
                for (int ni = 0; ni < 4; ++ni)
                    acc[mi][ni] = (f32x4){0.f, 0.f, 0.f, 0.f};

            __builtin_amdgcn_s_setprio(1);             // T5: favor MFMA waves vs producers
            #pragma unroll
            for (int kk = 0; kk < 8; ++kk) {
                const int kg = kk * 4 + lk8;
                bf16x8 af[2], bfr[4];
                #pragma unroll
                for (int mi = 0; mi < 2; ++mi) {
                    const int row = mi * 16 + lr;
                    af[mi] = t_lds[qb][row * 32 + (kg ^ (row & 7))];
                }
                #pragma unroll
                for (int ni = 0; ni < 4; ++ni)
                    bfr[ni] = pvF[(kk * 4 + ni) * 64];   // dense 1KB wave burst
                #pragma unroll
                for (int mi = 0; mi < 2; ++mi)
                    #pragma unroll
                    for (int ni = 0; ni < 4; ++ni)
                        acc[mi][ni] = __builtin_amdgcn_mfma_f32_16x16x32_bf16(
                            bfr[ni], af[mi], acc[mi][ni], 0, 0, 0);
            }
            __builtin_amdgcn_s_setprio(0);

            float* obase = out + ((size_t)(b * OH + oh) * OW + q * 32) * FF;
            #pragma unroll
            for (int ni = 0; ni < 4; ++ni) {
                const int f0 = wc * 64 + ni * 16 + lk8 * 4;
                #pragma unroll
                for (int mi = 0; mi < 2; ++mi) {
                    const int ow = mi * 16 + lr;
                    f32x4 v = acc[mi][ni] + bv[ni];
                    v[0] = v[0] > 0.f ? v[0] : 0.f;
                    v[1] = v[1] > 0.f ? v[1] : 0.f;
                    v[2] = v[2] > 0.f ? v[2] : 0.f;
                    v[3] = v[3] > 0.f ? v[3] : 0.f;
                    *reinterpret_cast<f32x4*>(&obase[(size_t)ow * FF + f0]) = v;
                }
            }
        }
    }
}

extern "C" void kernel_launch(void* const* d_in, const int* in_sizes, int n_in,
                              void* d_out, int out_size, void* d_ws, size_t ws_size,
                              hipStream_t stream) {
    (void)in_sizes; (void)n_in; (void)out_size; (void)ws_size;
    const float* X    = (const float*)d_in[0];
    const float* dw   = (const float*)d_in[1];
    const float* pw   = (const float*)d_in[2];
    const float* bias = (const float*)d_in[3];
    float* out = (float*)d_out;
    short* pwtF = (short*)d_ws;                       // 8192 entries * 16B = 128 KiB

    prep_kernel<<<dim3(32), dim3(256), 0, stream>>>(pw, pwtF);
    sepconvt_kernel<<<dim3(BB * OH), dim3(512), 0, stream>>>(X, dw, pwtF, bias, out);
}

// Round 27
// 125.633 us; speedup vs baseline: 1.0914x; 1.0914x over previous
//
#include <hip/hip_runtime.h>
#include <hip/hip_bf16.h>

// Shapes (fixed by the reference)
#define BB 16
#define HH 64
#define WW 64
#define CC 256
#define OH 128
#define OW 128
#define FF 256

typedef __attribute__((ext_vector_type(8))) short bf16x8;
typedef __attribute__((ext_vector_type(4))) float f32x4;

// RNE float -> bf16 bits
__device__ __forceinline__ short f2bf(float x) {
    union { float f; unsigned u; } v; v.f = x;
    unsigned r = v.u + 0x7fffu + ((v.u >> 16) & 1u);
    return (short)(r >> 16);
}

// packed f32x2 -> bf16x2 (1 VALU instr)
__device__ __forceinline__ unsigned cvtpk(float lo, float hi) {
    unsigned r;
    asm("v_cvt_pk_bf16_f32 %0, %1, %2" : "=v"(r) : "v"(lo), "v"(hi));
    return r;
}

// prep: 32 blocks build pwtF = pw in MFMA fragment-linear order:
//   entry e = ((wc*8 + kk)*4 + ni)*64 + lane (bf16x8); holds pw[c0..c0+7][f]
//   with f = wc*64+ni*16+(lane&15), c0 = kk*32+(lane>>4)*8.
__global__ void prep_kernel(const float* __restrict__ pw, short* __restrict__ pwtF) {
    const int e    = blockIdx.x * 256 + threadIdx.x;
    const int lane = e & 63;
    const int ni   = (e >> 6) & 3;
    const int kk   = (e >> 8) & 7;
    const int wc   = e >> 11;
    const int f    = wc * 64 + ni * 16 + (lane & 15);
    const int c0   = kk * 32 + (lane >> 4) * 8;
    bf16x8 v;
    #pragma unroll
    for (int j = 0; j < 8; ++j) v[j] = f2bf(pw[(size_t)(c0 + j) * FF + f]);
    reinterpret_cast<bf16x8*>(pwtF)[e] = v;
}

// One block = one (b, oh) output row, 4 quarters of 32 ow.
// Waves 0-3 = producers: wave-private global_load_lds X staging (counted vmcnt)
//   + depthwise from LDS -> t_lds[q&1]. Wave w owns ow chunk [q*32+w*8, +8),
//   lane owns 4 channels -> all staging/reads perfectly linear, and each wave
//   reads ONLY the xraw window it staged itself (per-wave vmcnt is sound).
// Waves 4-7 = consumers: MFMA pointwise (fragment-linear B) + f32x4 stores.
// Raw s_barrier (asm, memory clobber) between quarters; vmcnt never drained.
__global__ __launch_bounds__(512, 2)
void sepconvt_kernel(const float* __restrict__ X,
                     const float* __restrict__ dw,
                     const short* __restrict__ pwtF,
                     const float* __restrict__ bias,
                     float* __restrict__ out) {
    __shared__ __align__(16) char xraw[98304];     // 2 bufs x 4 waves x [2 rows][6 cols][256ch f32]
    __shared__ bf16x8 t_lds[2][32 * 32];           // 2 x 16 KiB

    const int tid  = threadIdx.x;
    const int wid  = tid >> 6;
    const int lane = tid & 63;
    const int blk  = blockIdx.x;          // b*OH + oh
    const int oh = blk & (OH - 1);
    const int b  = blk >> 7;

    // Row taps: even oh -> (r=1, i=oh/2), (r=3, i=oh/2-1); odd -> (r=0,(oh+1)/2),(r=2,(oh-1)/2)
    int r0, r1, i0, i1;
    if (oh & 1) { r0 = 0; i0 = (oh + 1) >> 1; r1 = 2; i1 = (oh - 1) >> 1; }
    else        { r0 = 1; i0 = oh >> 1;       r1 = 3; i1 = (oh >> 1) - 1; }
    const bool va0 = (unsigned)i0 < HH;
    const bool va1 = (unsigned)i1 < HH;

    if (wid < 4) {
        // ---------------- producer persona ----------------
        const int w  = wid;
        const int c4 = lane << 2;         // 4-channel base
        const float* Xr0 = X + (size_t)(b * HH + (va0 ? i0 : 0)) * WW * CC + c4;
        const float* Xr1 = X + (size_t)(b * HH + (va1 ? i1 : 0)) * WW * CC + c4;

        // weights wt[row][p][tap]: p=0 even ow (je=s1, jo=s3), p=1 odd (je=s0, jo=s2)
        float4 wt[2][2][2];
        {
            const float4 z = {0.f, 0.f, 0.f, 0.f};
            #pragma unroll
            for (int r = 0; r < 2; ++r) {
                const int rr = r ? r1 : r0;
                const bool va = r ? va1 : va0;
                float4 s0 = *reinterpret_cast<const float4*>(dw + (rr * 4 + 0) * CC + c4);
                float4 s1 = *reinterpret_cast<const float4*>(dw + (rr * 4 + 1) * CC + c4);
                float4 s2 = *reinterpret_cast<const float4*>(dw + (rr * 4 + 2) * CC + c4);
                float4 s3 = *reinterpret_cast<const float4*>(dw + (rr * 4 + 3) * CC + c4);
                wt[r][0][0] = va ? s1 : z;
                wt[r][0][1] = va ? s3 : z;
                wt[r][1][0] = va ? s0 : z;
                wt[r][1][1] = va ? s2 : z;
            }
        }

        // stage quarter q's wave-private window into buffer qb (12 x 1KB DMA)
        auto STAGE = [&](int q, int qb) {
            const int W0  = q * 32 + w * 8;
            const int jlo = (W0 >> 1) - 1;
            const int base = qb * 49152 + w * 12288;
            #pragma unroll
            for (int ci = 0; ci < 6; ++ci) {
                int j = jlo + ci;
                j = j < 0 ? 0 : (j > WW - 1 ? WW - 1 : j);
                __builtin_amdgcn_global_load_lds(
                    (const __attribute__((address_space(1))) unsigned*)(Xr0 + (size_t)j * CC),
                    (__attribute__((address_space(3))) unsigned*)(xraw + base + ci * 1024),
                    16, 0, 0);
                __builtin_amdgcn_global_load_lds(
                    (const __attribute__((address_space(1))) unsigned*)(Xr1 + (size_t)j * CC),
                    (__attribute__((address_space(3))) unsigned*)(xraw + base + 6144 + ci * 1024),
                    16, 0, 0);
            }
        };

        auto LC = [&](const char* xw, int ci, float4& x0, float4& x1) {
            x0 = *reinterpret_cast<const float4*>(xw + ci * 1024 + lane * 16);
            x1 = *reinterpret_cast<const float4*>(xw + 6144 + ci * 1024 + lane * 16);
        };

        auto EMIT = [&](int qb, int owl, int p,
                        const float4& xe0, const float4& xe1,
                        const float4& xo0, const float4& xo1) {
            const float4 we0 = wt[0][p][0], wo0 = wt[0][p][1];
            const float4 we1 = wt[1][p][0], wo1 = wt[1][p][1];
            float a0 = we0.x * xe0.x + wo0.x * xo0.x + we1.x * xe1.x + wo1.x * xo1.x;
            float a1 = we0.y * xe0.y + wo0.y * xo0.y + we1.y * xe1.y + wo1.y * xo1.y;
            float a2 = we0.z * xe0.z + wo0.z * xo0.z + we1.z * xe1.z + wo1.z * xo1.z;
            float a3 = we0.w * xe0.w + wo0.w * xo0.w + we1.w * xe1.w + wo1.w * xo1.w;
            unsigned* dst = reinterpret_cast<unsigned*>(
                reinterpret_cast<char*>(&t_lds[qb][0]) + owl * 512 +
                (((lane >> 1) ^ (owl & 7)) << 4) + ((lane & 1) << 3));
            dst[0] = cvtpk(a0, a1);
            dst[1] = cvtpk(a2, a3);
        };

        auto PRODUCE = [&](int q, int qb) {
            const char* xw = xraw + qb * 49152 + w * 12288;
            const int W0 = q * 32 + w * 8;
            const int o0 = w * 8;
            float4 xo0, xo1, xe0, xe1;
            LC(xw, 0, xo0, xo1);
            LC(xw, 1, xe0, xe1);
            if (W0 == 0) { xo0 = (float4){0,0,0,0}; xo1 = (float4){0,0,0,0}; }
            EMIT(qb, o0 + 0, 0, xe0, xe1, xo0, xo1);
            xo0 = xe0; xo1 = xe1; LC(xw, 2, xe0, xe1);
            EMIT(qb, o0 + 1, 1, xe0, xe1, xo0, xo1);
            EMIT(qb, o0 + 2, 0, xe0, xe1, xo0, xo1);
            xo0 = xe0; xo1 = xe1; LC(xw, 3, xe0, xe1);
            EMIT(qb, o0 + 3, 1, xe0, xe1, xo0, xo1);
            EMIT(qb, o0 + 4, 0, xe0, xe1, xo0, xo1);
            xo0 = xe0; xo1 = xe1; LC(xw, 4, xe0, xe1);
            EMIT(qb, o0 + 5, 1, xe0, xe1, xo0, xo1);
            EMIT(qb, o0 + 6, 0, xe0, xe1, xo0, xo1);
            xo0 = xe0; xo1 = xe1; LC(xw, 5, xe0, xe1);
            if (W0 == 120) { xe0 = (float4){0,0,0,0}; xe1 = (float4){0,0,0,0}; }
            EMIT(qb, o0 + 7, 1, xe0, xe1, xo0, xo1);
        };

        STAGE(0, 0);
        #pragma unroll
        for (int q = 0; q < 4; ++q) {
            if (q < 3) {
                STAGE(q + 1, (q + 1) & 1);
                asm volatile("s_waitcnt vmcnt(12)" ::: "memory");  // own S(q) landed; S(q+1) in flight
            } else {
                asm volatile("s_waitcnt vmcnt(0)" ::: "memory");
            }
            __builtin_amdgcn_sched_barrier(0);
            PRODUCE(q, q & 1);
            asm volatile("s_waitcnt lgkmcnt(0)" ::: "memory");     // own t_lds writes drained
            __builtin_amdgcn_sched_barrier(0);
            asm volatile("s_barrier" ::: "memory");                // tile q ready
        }
    } else {
        // ---------------- consumer persona ----------------
        const int wc  = wid - 4;          // 0..3 -> f block
        const int lr  = lane & 15;
        const int lk8 = lane >> 4;
        const bf16x8* pvF = reinterpret_cast<const bf16x8*>(pwtF) + (size_t)wc * 2048 + lane;

        f32x4 bv[4];
        #pragma unroll
        for (int ni = 0; ni < 4; ++ni)
            bv[ni] = *reinterpret_cast<const f32x4*>(&bias[wc * 64 + ni * 16 + lk8 * 4]);

        #pragma unroll
        for (int q = 0; q < 4; ++q) {
            asm volatile("s_barrier" ::: "memory");    // wait tile q
            __builtin_amdgcn_sched_barrier(0);
            const int qb = q & 1;

            f32x4 acc[2][4];
            #pragma unroll
            for (int mi = 0; mi < 2; ++mi)
                #pragma unroll
                for (int ni = 0; ni < 4; ++ni)
                    acc[mi][ni] = (f32x4){0.f, 0.f, 0.f, 0.f};

            #pragma unroll
            for (int kk = 0; kk < 8; ++kk) {
                const int kg = kk * 4 + lk8;
                bf16x8 af[2], bfr[4];
                #pragma unroll
                for (int mi = 0; mi < 2; ++mi) {
                    const int row = mi * 16 + lr;
                    af[mi] = t_lds[qb][row * 32 + (kg ^ (row & 7))];
                }
                #pragma unroll
                for (int ni = 0; ni < 4; ++ni)
                    bfr[ni] = pvF[(kk * 4 + ni) * 64];   // dense 1KB wave burst
                #pragma unroll
                for (int mi = 0; mi < 2; ++mi)
                    #pragma unroll
                    for (int ni = 0; ni < 4; ++ni)
                        acc[mi][ni] = __builtin_amdgcn_mfma_f32_16x16x32_bf16(
                            bfr[ni], af[mi], acc[mi][ni], 0, 0, 0);
            }

            float* obase = out + ((size_t)(b * OH + oh) * OW + q * 32) * FF;
            #pragma unroll
            for (int ni = 0; ni < 4; ++ni) {
                const int f0 = wc * 64 + ni * 16 + lk8 * 4;
                #pragma unroll
                for (int mi = 0; mi < 2; ++mi) {
                    const int ow = mi * 16 + lr;
                    f32x4 v = acc[mi][ni] + bv[ni];
                    v[0] = v[0] > 0.f ? v[0] : 0.f;
                    v[1] = v[1] > 0.f ? v[1] : 0.f;
                    v[2] = v[2] > 0.f ? v[2] : 0.f;
                    v[3] = v[3] > 0.f ? v[3] : 0.f;
                    *reinterpret_cast<f32x4*>(&obase[(size_t)ow * FF + f0]) = v;
                }
            }
        }
    }
}

extern "C" void kernel_launch(void* const* d_in, const int* in_sizes, int n_in,
                              void* d_out, int out_size, void* d_ws, size_t ws_size,
                              hipStream_t stream) {
    (void)in_sizes; (void)n_in; (void)out_size; (void)ws_size;
    const float* X    = (const float*)d_in[0];
    const float* dw   = (const float*)d_in[1];
    const float* pw   = (const float*)d_in[2];
    const float* bias = (const float*)d_in[3];
    float* out = (float*)d_out;
    short* pwtF = (short*)d_ws;                       // 8192 entries * 16B = 128 KiB

    prep_kernel<<<dim3(32), dim3(256), 0, stream>>>(pw, pwtF);
    sepconvt_kernel<<<dim3(BB * OH), dim3(512), 0, stream>>>(X, dw, pwtF, bias, out);
}